// Round 1
// baseline (130.446 us; speedup 1.0000x reference)
//
#include <hip/hip_runtime.h>
#include <math.h>

// Problem constants (b=2, L=4096, H=16, dh=ds=64, CHUNK=64)
#define LSEQ 4096
#define NH   16
#define DH   64
#define CH   64      // chunk size
#define NCH  64      // number of chunks = LSEQ/CH
#define LDP  68      // padded LDS row stride in floats (16B-aligned quads, bank stagger)

union F4 { float4 v; float f[4]; };

__device__ __forceinline__ float4 ld4(const float* p) {
    return *reinterpret_cast<const float4*>(p);
}
__device__ __forceinline__ void st4(float* p, float4 v) {
    *reinterpret_cast<float4*>(p) = v;
}

// ---------------------------------------------------------------------------
// Kernel 1: per-chunk work. One block per (b, h, n). 256 threads.
//   - load X,B,C chunk into LDS
//   - chunk surprise -> alpha -> A_mod cumsum
//   - Y_intra -> d_out
//   - h_final -> ws, decay_chunk -> ws, decay_from_start -> ws
// ---------------------------------------------------------------------------
__global__ __launch_bounds__(256) void ssd_k1(
    const float* __restrict__ X, const float* __restrict__ A,
    const float* __restrict__ B, const float* __restrict__ C,
    const float* __restrict__ l2ab, const float* __restrict__ l2b,
    const float* __restrict__ ema,
    float* __restrict__ Y, float* __restrict__ hf,
    float* __restrict__ dcb, float* __restrict__ dfs)
{
    __shared__ __align__(16) float sX[CH * LDP];
    __shared__ __align__(16) float sB[CH * LDP];
    __shared__ __align__(16) float sC[CH * LDP];
    __shared__ float sA[CH], sAcs[CH], sDte[CH];
    __shared__ float red[4];

    const int tid  = threadIdx.x;
    const int blk  = blockIdx.x;             // (bb*NH + h)*NCH + nidx
    const int nidx = blk & (NCH - 1);
    const int h    = (blk >> 6) & (NH - 1);
    const int bb   = blk >> 10;
    const size_t rowstride = (size_t)NH * DH;                       // 1024
    const size_t base = ((size_t)(bb * LSEQ + nidx * CH) * NH + h) * DH;

    // ---- stage chunk (float4 coalesced) ----
    #pragma unroll
    for (int m = 0; m < 4; ++m) {
        int p = tid + 256 * m;       // quad id 0..1023
        int c = p >> 4, q = p & 15;
        size_t g = base + (size_t)c * rowstride + q * 4;
        st4(&sX[c * LDP + q * 4], ld4(&X[g]));
        st4(&sB[c * LDP + q * 4], ld4(&B[g]));
        st4(&sC[c * LDP + q * 4], ld4(&C[g]));
    }
    if (tid < CH) sA[tid] = A[(size_t)(bb * LSEQ + nidx * CH + tid) * NH + h];
    __syncthreads();

    const int tx = tid & 15, ty = tid >> 4;
    const int col0 = tx * 4;   // d / j / p base
    const int row0 = ty * 4;   // s / i base

    // ---- surprise: sum_{s,d} (sum_c B[c,s] X[c,d])^2 ----
    float bx[4][4];
    #pragma unroll
    for (int r = 0; r < 4; ++r)
        #pragma unroll
        for (int q = 0; q < 4; ++q) bx[r][q] = 0.f;
    for (int c = 0; c < CH; ++c) {
        F4 b4, x4;
        b4.v = ld4(&sB[c * LDP + row0]);
        x4.v = ld4(&sX[c * LDP + col0]);
        #pragma unroll
        for (int r = 0; r < 4; ++r)
            #pragma unroll
            for (int q = 0; q < 4; ++q)
                bx[r][q] = fmaf(b4.f[r], x4.f[q], bx[r][q]);
    }
    float acc = 0.f;
    #pragma unroll
    for (int r = 0; r < 4; ++r)
        #pragma unroll
        for (int q = 0; q < 4; ++q) acc += bx[r][q] * bx[r][q];
    #pragma unroll
    for (int off = 32; off > 0; off >>= 1) acc += __shfl_down(acc, off, 64);
    if ((tid & 63) == 0) red[tid >> 6] = acc;
    __syncthreads();
    if (tid == 0) {
        float cs  = (red[0] + red[1] + red[2] + red[3]) * (1.f / 4096.f);
        float l2c = fminf(fmaxf(l2ab[h], -3.32f), -0.015f);
        float ab_ = 1.f - exp2f(l2c);
        float bt  = exp2f(fminf(fmaxf(l2b[h], -2.f), 2.f));
        float nrm = cs / (ema[h] + 1e-6f);
        float boost = fmaxf(tanhf(bt * nrm), 0.f);
        float alpha = fminf(fmaxf(ab_ + (1.f - ab_) * boost, 0.01f), 0.999f);
        float scale = 1.f - alpha;
        float run = 0.f;
        for (int c = 0; c < CH; ++c) { run = fmaf(sA[c], scale, run); sAcs[c] = run; }
        dcb[blk] = expf(run);                       // decay_chunk
    }
    __syncthreads();
    if (tid < CH) {
        sDte[tid] = expf(sAcs[CH - 1] - sAcs[tid]); // decay_to_end
        dfs[(size_t)blk * CH + tid] = expf(sAcs[tid]); // decay_from_start
    }
    __syncthreads();

    // ---- CB[i,j] = sum_d C[i,d] B[j,d] ----
    float cb[4][4];
    #pragma unroll
    for (int r = 0; r < 4; ++r)
        #pragma unroll
        for (int q = 0; q < 4; ++q) cb[r][q] = 0.f;
    for (int d0 = 0; d0 < CH; d0 += 4) {
        F4 crow[4], brow[4];
        #pragma unroll
        for (int r = 0; r < 4; ++r) crow[r].v = ld4(&sC[(row0 + r) * LDP + d0]);
        #pragma unroll
        for (int q = 0; q < 4; ++q) brow[q].v = ld4(&sB[(col0 + q) * LDP + d0]);
        #pragma unroll
        for (int r = 0; r < 4; ++r)
            #pragma unroll
            for (int q = 0; q < 4; ++q) {
                float s = 0.f;
                #pragma unroll
                for (int k = 0; k < 4; ++k) s = fmaf(crow[r].f[k], brow[q].f[k], s);
                cb[r][q] += s;
            }
    }
    __syncthreads();
    // ---- overwrite sC with T = Lmat .* CB ----
    #pragma unroll
    for (int r = 0; r < 4; ++r) {
        int i = row0 + r;
        float ai = sAcs[i];
        #pragma unroll
        for (int q = 0; q < 4; ++q) {
            int j = col0 + q;
            float t = (j <= i) ? expf(ai - sAcs[j]) * cb[r][q] : 0.f;
            sC[i * LDP + j] = t;
        }
    }
    __syncthreads();

    // ---- Y_intra[i,d] = sum_j T[i,j] X[j,d] ----
    float yv[4][4];
    #pragma unroll
    for (int r = 0; r < 4; ++r)
        #pragma unroll
        for (int q = 0; q < 4; ++q) yv[r][q] = 0.f;
    for (int j0 = 0; j0 < CH; j0 += 4) {
        F4 trow[4], xrow[4];
        #pragma unroll
        for (int r = 0; r < 4; ++r) trow[r].v = ld4(&sC[(row0 + r) * LDP + j0]);
        #pragma unroll
        for (int jj = 0; jj < 4; ++jj) xrow[jj].v = ld4(&sX[(j0 + jj) * LDP + col0]);
        #pragma unroll
        for (int r = 0; r < 4; ++r)
            #pragma unroll
            for (int jj = 0; jj < 4; ++jj)
                #pragma unroll
                for (int q = 0; q < 4; ++q)
                    yv[r][q] = fmaf(trow[r].f[jj], xrow[jj].f[q], yv[r][q]);
    }
    #pragma unroll
    for (int r = 0; r < 4; ++r) {
        F4 o; o.f[0] = yv[r][0]; o.f[1] = yv[r][1]; o.f[2] = yv[r][2]; o.f[3] = yv[r][3];
        st4(&Y[base + (size_t)(row0 + r) * rowstride + col0], o.v);
    }

    // ---- h_final[s,d] = sum_c dte[c] B[c,s] X[c,d] ----
    float hv[4][4];
    #pragma unroll
    for (int r = 0; r < 4; ++r)
        #pragma unroll
        for (int q = 0; q < 4; ++q) hv[r][q] = 0.f;
    for (int c = 0; c < CH; ++c) {
        float dte = sDte[c];
        F4 b4, x4;
        b4.v = ld4(&sB[c * LDP + row0]);
        x4.v = ld4(&sX[c * LDP + col0]);
        #pragma unroll
        for (int r = 0; r < 4; ++r) {
            float bw = b4.f[r] * dte;
            #pragma unroll
            for (int q = 0; q < 4; ++q)
                hv[r][q] = fmaf(bw, x4.f[q], hv[r][q]);
        }
    }
    #pragma unroll
    for (int r = 0; r < 4; ++r) {
        F4 o; o.f[0] = hv[r][0]; o.f[1] = hv[r][1]; o.f[2] = hv[r][2]; o.f[3] = hv[r][3];
        st4(&hf[(size_t)blk * (CH * DH) + (size_t)(row0 + r) * DH + col0], o.v);
    }
}

// ---------------------------------------------------------------------------
// Kernel 2: sequential inter-chunk scan per (b,h). One block per (b,h),
// 1024 threads; each thread owns 4 consecutive state elements.
// In-place: hf[k] (h_final) is replaced by h_inter[k] (state BEFORE chunk k).
// ---------------------------------------------------------------------------
__global__ __launch_bounds__(1024) void ssd_k2(
    float* __restrict__ hf, const float* __restrict__ dcb)
{
    __shared__ float sdc[NCH];
    const int tid = threadIdx.x;
    const int bh  = blockIdx.x;
    if (tid < NCH) sdc[tid] = dcb[bh * NCH + tid];
    __syncthreads();
    size_t base = (size_t)bh * NCH * (CH * DH) + (size_t)tid * 4;
    F4 carry; carry.f[0] = carry.f[1] = carry.f[2] = carry.f[3] = 0.f;
    for (int k = 0; k < NCH; ++k) {
        float* p = &hf[base + (size_t)k * (CH * DH)];
        F4 v; v.v = ld4(p);
        st4(p, carry.v);
        float d = sdc[k];
        #pragma unroll
        for (int e = 0; e < 4; ++e) carry.f[e] = fmaf(d, carry.f[e], v.f[e]);
    }
}

// ---------------------------------------------------------------------------
// Kernel 3: Y_inter[i,p] = dfs[i] * sum_s C[i,s] h_inter[s,p], added to Y.
// One block per (b,h,n). 256 threads.
// ---------------------------------------------------------------------------
__global__ __launch_bounds__(256) void ssd_k3(
    const float* __restrict__ C, const float* __restrict__ hI,
    const float* __restrict__ dfs, float* __restrict__ Y)
{
    __shared__ __align__(16) float sC[CH * LDP];
    __shared__ __align__(16) float sH[CH * LDP];
    __shared__ float sF[CH];

    const int tid  = threadIdx.x;
    const int blk  = blockIdx.x;
    const int nidx = blk & (NCH - 1);
    const int h    = (blk >> 6) & (NH - 1);
    const int bb   = blk >> 10;
    const size_t rowstride = (size_t)NH * DH;
    const size_t base = ((size_t)(bb * LSEQ + nidx * CH) * NH + h) * DH;

    #pragma unroll
    for (int m = 0; m < 4; ++m) {
        int p = tid + 256 * m;
        int c = p >> 4, q = p & 15;
        st4(&sC[c * LDP + q * 4], ld4(&C[base + (size_t)c * rowstride + q * 4]));
        st4(&sH[c * LDP + q * 4], ld4(&hI[(size_t)blk * (CH * DH) + (size_t)p * 4]));
    }
    if (tid < CH) sF[tid] = dfs[(size_t)blk * CH + tid];
    __syncthreads();

    const int tx = tid & 15, ty = tid >> 4;
    const int col0 = tx * 4;
    const int row0 = ty * 4;

    float yv[4][4];
    #pragma unroll
    for (int r = 0; r < 4; ++r)
        #pragma unroll
        for (int q = 0; q < 4; ++q) yv[r][q] = 0.f;
    for (int s0 = 0; s0 < CH; s0 += 4) {
        F4 crow[4], hrow[4];
        #pragma unroll
        for (int r = 0; r < 4; ++r) crow[r].v = ld4(&sC[(row0 + r) * LDP + s0]);
        #pragma unroll
        for (int ss = 0; ss < 4; ++ss) hrow[ss].v = ld4(&sH[(s0 + ss) * LDP + col0]);
        #pragma unroll
        for (int r = 0; r < 4; ++r)
            #pragma unroll
            for (int ss = 0; ss < 4; ++ss)
                #pragma unroll
                for (int q = 0; q < 4; ++q)
                    yv[r][q] = fmaf(crow[r].f[ss], hrow[ss].f[q], yv[r][q]);
    }
    #pragma unroll
    for (int r = 0; r < 4; ++r) {
        float f = sF[row0 + r];
        size_t g = base + (size_t)(row0 + r) * rowstride + col0;
        F4 o; o.v = ld4(&Y[g]);
        #pragma unroll
        for (int q = 0; q < 4; ++q) o.f[q] = fmaf(f, yv[r][q], o.f[q]);
        st4(&Y[g], o.v);
    }
}

// ---------------------------------------------------------------------------
extern "C" void kernel_launch(void* const* d_in, const int* in_sizes, int n_in,
                              void* d_out, int out_size, void* d_ws, size_t ws_size,
                              hipStream_t stream)
{
    const float* X    = (const float*)d_in[0];
    const float* A    = (const float*)d_in[1];
    const float* B    = (const float*)d_in[2];
    const float* C    = (const float*)d_in[3];
    const float* l2ab = (const float*)d_in[4];
    const float* l2b  = (const float*)d_in[5];
    const float* ema  = (const float*)d_in[6];
    float* Y = (float*)d_out;

    // workspace layout (floats): hf [2*16*64*4096] | dcb [2048] | dfs [131072]
    // total = 34,086,912 bytes
    float* hf  = (float*)d_ws;
    float* dcb = hf + (size_t)2 * NH * NCH * (CH * DH);
    float* dfs = dcb + (size_t)2 * NH * NCH;

    const int nblk = 2 * NH * NCH;   // 2048
    ssd_k1<<<nblk, 256, 0, stream>>>(X, A, B, C, l2ab, l2b, ema, Y, hf, dcb, dfs);
    ssd_k2<<<2 * NH, 1024, 0, stream>>>(hf, dcb);
    ssd_k3<<<nblk, 256, 0, stream>>>(C, hf, dfs, Y);
}

// Round 2
// 79.107 us; speedup vs baseline: 1.6490x; 1.6490x over previous
//
#include <hip/hip_runtime.h>
#include <hip/hip_bf16.h>
#include <math.h>

// Problem constants (b=2, L=4096, H=16, dh=ds=64, CHUNK=64)
#define LSEQ 4096
#define NH   16
#define DH   64
#define CH   64
#define NCH  64
#define LDT  72   // bf16 LDS row stride: 144B rows -> 16B aligned, <=2-way conflicts

typedef __attribute__((ext_vector_type(8))) short bf16x8;
typedef __attribute__((ext_vector_type(4))) short s16x4;
typedef __attribute__((ext_vector_type(4))) float f32x4;

#define MFMA16(a, b, c) __builtin_amdgcn_mfma_f32_16x16x32_bf16((a), (b), (c), 0, 0, 0)

__device__ __forceinline__ float4 ld4(const float* p) {
    return *reinterpret_cast<const float4*>(p);
}
__device__ __forceinline__ short f2b(float x) {
    __hip_bfloat16 h = __float2bfloat16(x);
    return *reinterpret_cast<short*>(&h);
}
__device__ __forceinline__ float b2f(short s) {
    union { unsigned u; float f; } v;
    v.u = ((unsigned)(unsigned short)s) << 16;
    return v.f;
}
__device__ __forceinline__ s16x4 pack4(float a, float b, float c, float d) {
    s16x4 r; r.x = f2b(a); r.y = f2b(b); r.z = f2b(c); r.w = f2b(d); return r;
}

// ---------------------------------------------------------------------------
// Kernel 1: per-chunk MFMA work. One block per (b,h,n). 256 threads = 4 waves.
// Fragment map (m89-verified, 16x16x32 bf16):
//   A: lane supplies A[row=lane&15][k = k0 + 8*(lane>>4) + i]
//   B: lane supplies B[k = k0 + 8*(lane>>4) + i][col=lane&15]
//   D: lane holds D[row = 4*(lane>>4)+reg][col=lane&15]
// => A-operand matrices stored [M][K] K-contig, B-operand stored [N][K] K-contig.
// LDS tiles: sXT = X^T [d][c], sBT = B^T [s][c] (later dte-scaled B'^T),
//            sB = B [c][s], sC = C [i][d], sT = Lmat.*CB [i][j].
// ---------------------------------------------------------------------------
__global__ __launch_bounds__(256) void ssd_k1(
    const float* __restrict__ X, const float* __restrict__ A,
    const float* __restrict__ B, const float* __restrict__ C,
    const float* __restrict__ l2ab, const float* __restrict__ l2b,
    const float* __restrict__ ema,
    float* __restrict__ Y, float* __restrict__ hf,
    float* __restrict__ dcb, float* __restrict__ dfs)
{
    __shared__ __align__(16) short sXT[CH * LDT];
    __shared__ __align__(16) short sBT[CH * LDT];
    __shared__ __align__(16) short sB [CH * LDT];
    __shared__ __align__(16) short sC [CH * LDT];
    __shared__ __align__(16) short sT [CH * LDT];
    __shared__ float sA[CH], sAcs[CH], sDte[CH], red[4];

    const int tid  = threadIdx.x;
    const int blk  = blockIdx.x;
    const int nidx = blk & (NCH - 1);
    const int h    = (blk >> 6) & (NH - 1);
    const int bb   = blk >> 10;
    const size_t base = ((size_t)(bb * LSEQ + nidx * CH) * NH + h) * DH;

    // ---- stage: X -> sXT (scatter transpose), B -> sB + sBT, C -> sC ----
    #pragma unroll
    for (int m = 0; m < 4; ++m) {
        int p = tid + 256 * m;
        int c = p >> 4, q = p & 15, d0 = q * 4;
        size_t g = base + (size_t)c * 1024 + d0;
        float4 xv = ld4(&X[g]);
        float4 bv = ld4(&B[g]);
        float4 cv = ld4(&C[g]);
        *reinterpret_cast<s16x4*>(&sC[c * LDT + d0]) = pack4(cv.x, cv.y, cv.z, cv.w);
        *reinterpret_cast<s16x4*>(&sB[c * LDT + d0]) = pack4(bv.x, bv.y, bv.z, bv.w);
        float xf[4] = {xv.x, xv.y, xv.z, xv.w};
        float bf[4] = {bv.x, bv.y, bv.z, bv.w};
        #pragma unroll
        for (int ee = 0; ee < 4; ++ee) {
            int e = (ee + q) & 3;   // lane-staggered order breaks write-bank aliasing
            sXT[(d0 + e) * LDT + c] = f2b(xf[e]);
            sBT[(d0 + e) * LDT + c] = f2b(bf[e]);
        }
    }
    if (tid < CH) sA[tid] = A[(size_t)(bb * LSEQ + nidx * CH + tid) * NH + h];
    __syncthreads();

    const int lane = tid & 63;
    const int w    = tid >> 6;       // wave id -> row slab 16w..16w+15
    const int rb   = 16 * w;
    const int fr   = lane & 15;
    const int ko   = 8 * (lane >> 4);

    const f32x4 zf = {0.f, 0.f, 0.f, 0.f};

    // ---- phase 2: BX = B^T X  (A=sBT, Bop=sXT); surprise = ||BX||^2 ----
    f32x4 acc0[4] = {zf, zf, zf, zf};
    #pragma unroll
    for (int k0 = 0; k0 < 64; k0 += 32) {
        bf16x8 a = *reinterpret_cast<const bf16x8*>(&sBT[(rb + fr) * LDT + k0 + ko]);
        #pragma unroll
        for (int n = 0; n < 4; ++n) {
            bf16x8 b = *reinterpret_cast<const bf16x8*>(&sXT[(16 * n + fr) * LDT + k0 + ko]);
            acc0[n] = MFMA16(a, b, acc0[n]);
        }
    }
    float ss = 0.f;
    #pragma unroll
    for (int n = 0; n < 4; ++n)
        #pragma unroll
        for (int r = 0; r < 4; ++r) ss += acc0[n][r] * acc0[n][r];
    #pragma unroll
    for (int off = 32; off > 0; off >>= 1) ss += __shfl_down(ss, off, 64);
    if (lane == 0) red[w] = ss;
    __syncthreads();

    // ---- phase 3: gate + wave-parallel inclusive scan of A_mod (wave 0) ----
    if (tid < CH) {
        float surprise = (red[0] + red[1] + red[2] + red[3]) * (1.f / 4096.f);
        float l2c   = fminf(fmaxf(l2ab[h], -3.32f), -0.015f);
        float ab_   = 1.f - exp2f(l2c);
        float bt    = exp2f(fminf(fmaxf(l2b[h], -2.f), 2.f));
        float nrm   = surprise / (ema[h] + 1e-6f);
        float boost = fmaxf(tanhf(bt * nrm), 0.f);
        float alpha = fminf(fmaxf(ab_ + (1.f - ab_) * boost, 0.01f), 0.999f);
        float scale = 1.f - alpha;
        float v = sA[tid] * scale;
        #pragma unroll
        for (int off = 1; off < 64; off <<= 1) {
            float t = __shfl_up(v, off, 64);
            if (tid >= off) v += t;
        }
        float tot = __shfl(v, 63, 64);
        sAcs[tid] = v;
        sDte[tid] = expf(tot - v);
        dfs[(size_t)blk * CH + tid] = expf(v);
        if (tid == 63) dcb[blk] = expf(tot);
    }
    __syncthreads();

    // ---- phase 4a: sBT -> B'^T in place (scale col c by dte[c]) ----
    #pragma unroll
    for (int m = 0; m < 4; ++m) {
        int p = tid + 256 * m;
        int s = p >> 4, c0 = 4 * (p & 15);
        s16x4 v = *reinterpret_cast<s16x4*>(&sBT[s * LDT + c0]);
        v.x = f2b(b2f(v.x) * sDte[c0]);
        v.y = f2b(b2f(v.y) * sDte[c0 + 1]);
        v.z = f2b(b2f(v.z) * sDte[c0 + 2]);
        v.w = f2b(b2f(v.w) * sDte[c0 + 3]);
        *reinterpret_cast<s16x4*>(&sBT[s * LDT + c0]) = v;
    }

    // ---- phase 4b: CB = C B^T (A=sC, Bop=sB) ----
    f32x4 acc1[4] = {zf, zf, zf, zf};
    #pragma unroll
    for (int k0 = 0; k0 < 64; k0 += 32) {
        bf16x8 a = *reinterpret_cast<const bf16x8*>(&sC[(rb + fr) * LDT + k0 + ko]);
        #pragma unroll
        for (int n = 0; n < 4; ++n) {
            bf16x8 b = *reinterpret_cast<const bf16x8*>(&sB[(16 * n + fr) * LDT + k0 + ko]);
            acc1[n] = MFMA16(a, b, acc1[n]);
        }
    }
    // ---- phase 4c: T[i][j] = (j<=i) ? exp(Acs_i - Acs_j) * CB : 0 ----
    #pragma unroll
    for (int n = 0; n < 4; ++n)
        #pragma unroll
        for (int r = 0; r < 4; ++r) {
            int i = rb + 4 * (lane >> 4) + r;
            int j = 16 * n + fr;
            float val = (j <= i) ? expf(sAcs[i] - sAcs[j]) * acc1[n][r] : 0.f;
            sT[i * LDT + j] = f2b(val);
        }
    __syncthreads();   // covers sBT rescale + sT visibility

    // ---- phase 5: Y_intra = T X (A=sT, Bop=sXT)
    //      phase 6: h_final^T = X^T B' (A=sXT, Bop=sBT) ----
    f32x4 acc2[4] = {zf, zf, zf, zf};
    f32x4 acc3[4] = {zf, zf, zf, zf};
    #pragma unroll
    for (int k0 = 0; k0 < 64; k0 += 32) {
        bf16x8 aT = *reinterpret_cast<const bf16x8*>(&sT [(rb + fr) * LDT + k0 + ko]);
        bf16x8 aX = *reinterpret_cast<const bf16x8*>(&sXT[(rb + fr) * LDT + k0 + ko]);
        #pragma unroll
        for (int n = 0; n < 4; ++n) {
            bf16x8 bX = *reinterpret_cast<const bf16x8*>(&sXT[(16 * n + fr) * LDT + k0 + ko]);
            bf16x8 bB = *reinterpret_cast<const bf16x8*>(&sBT[(16 * n + fr) * LDT + k0 + ko]);
            acc2[n] = MFMA16(aT, bX, acc2[n]);
            acc3[n] = MFMA16(aX, bB, acc3[n]);
        }
    }
    #pragma unroll
    for (int n = 0; n < 4; ++n)
        #pragma unroll
        for (int r = 0; r < 4; ++r) {
            int i = rb + 4 * (lane >> 4) + r;   // row index of D
            int c = 16 * n + fr;                // col index of D
            Y[base + (size_t)i * 1024 + c] = acc2[n][r];
            hf[(size_t)blk * (CH * DH) + (size_t)i * 64 + c] = acc3[n][r];  // [d][s]
        }
}

// ---------------------------------------------------------------------------
// Kernel 2: sequential inter-chunk scan. 128 blocks (4 per (b,h)), 1024 thr,
// each thread owns one state element. In-place: hf[k] -> h_inter[k].
// ---------------------------------------------------------------------------
__global__ __launch_bounds__(1024) void ssd_k2(
    float* __restrict__ hf, const float* __restrict__ dcb)
{
    __shared__ float sdc[NCH];
    const int tid = threadIdx.x;
    const int bh  = blockIdx.x >> 2;
    const int sub = blockIdx.x & 3;
    if (tid < NCH) sdc[tid] = dcb[bh * NCH + tid];
    __syncthreads();
    size_t base = (size_t)bh * NCH * (CH * DH) + (size_t)sub * 1024 + tid;
    float carry = 0.f;
    for (int k = 0; k < NCH; ++k) {
        float* p = &hf[base + (size_t)k * (CH * DH)];
        float v = *p;
        *p = carry;
        carry = fmaf(sdc[k], carry, v);
    }
}

// ---------------------------------------------------------------------------
// Kernel 3: Y += dfs[i] * (C @ h_inter). A=sC2 (C [i][s]), Bop=sHt (h^T [p][s]
// — exactly the ws layout written by k1/k2). One block per (b,h,n).
// ---------------------------------------------------------------------------
__global__ __launch_bounds__(256) void ssd_k3(
    const float* __restrict__ C, const float* __restrict__ hI,
    const float* __restrict__ dfs, float* __restrict__ Y)
{
    __shared__ __align__(16) short sC2[CH * LDT];
    __shared__ __align__(16) short sHt[CH * LDT];
    __shared__ float sF[CH];

    const int tid  = threadIdx.x;
    const int blk  = blockIdx.x;
    const int nidx = blk & (NCH - 1);
    const int h    = (blk >> 6) & (NH - 1);
    const int bb   = blk >> 10;
    const size_t base = ((size_t)(bb * LSEQ + nidx * CH) * NH + h) * DH;

    #pragma unroll
    for (int m = 0; m < 4; ++m) {
        int p = tid + 256 * m;
        int row = p >> 4, q = p & 15, d0 = q * 4;
        float4 cv = ld4(&C[base + (size_t)row * 1024 + d0]);
        float4 hv = ld4(&hI[(size_t)blk * (CH * DH) + (size_t)row * 64 + d0]);
        *reinterpret_cast<s16x4*>(&sC2[row * LDT + d0]) = pack4(cv.x, cv.y, cv.z, cv.w);
        *reinterpret_cast<s16x4*>(&sHt[row * LDT + d0]) = pack4(hv.x, hv.y, hv.z, hv.w);
    }
    if (tid < CH) sF[tid] = dfs[(size_t)blk * CH + tid];
    __syncthreads();

    const int lane = tid & 63;
    const int w    = tid >> 6;
    const int rb   = 16 * w;
    const int fr   = lane & 15;
    const int ko   = 8 * (lane >> 4);
    const f32x4 zf = {0.f, 0.f, 0.f, 0.f};

    f32x4 acc[4] = {zf, zf, zf, zf};
    #pragma unroll
    for (int k0 = 0; k0 < 64; k0 += 32) {
        bf16x8 a = *reinterpret_cast<const bf16x8*>(&sC2[(rb + fr) * LDT + k0 + ko]);
        #pragma unroll
        for (int n = 0; n < 4; ++n) {
            bf16x8 b = *reinterpret_cast<const bf16x8*>(&sHt[(16 * n + fr) * LDT + k0 + ko]);
            acc[n] = MFMA16(a, b, acc[n]);
        }
    }
    #pragma unroll
    for (int n = 0; n < 4; ++n)
        #pragma unroll
        for (int r = 0; r < 4; ++r) {
            int i = rb + 4 * (lane >> 4) + r;
            int p_ = 16 * n + fr;
            size_t g = base + (size_t)i * 1024 + p_;
            Y[g] = fmaf(sF[i], acc[n][r], Y[g]);
        }
}

// ---------------------------------------------------------------------------
extern "C" void kernel_launch(void* const* d_in, const int* in_sizes, int n_in,
                              void* d_out, int out_size, void* d_ws, size_t ws_size,
                              hipStream_t stream)
{
    const float* X    = (const float*)d_in[0];
    const float* A    = (const float*)d_in[1];
    const float* B    = (const float*)d_in[2];
    const float* C    = (const float*)d_in[3];
    const float* l2ab = (const float*)d_in[4];
    const float* l2b  = (const float*)d_in[5];
    const float* ema  = (const float*)d_in[6];
    float* Y = (float*)d_out;

    // ws layout (floats): hf [2*16*64*4096] | dcb [2048] | dfs [131072]
    float* hf  = (float*)d_ws;
    float* dcb = hf + (size_t)2 * NH * NCH * (CH * DH);
    float* dfs = dcb + (size_t)2 * NH * NCH;

    const int nblk = 2 * NH * NCH;   // 2048
    ssd_k1<<<nblk, 256, 0, stream>>>(X, A, B, C, l2ab, l2b, ema, Y, hf, dcb, dfs);
    ssd_k2<<<2 * NH * 4, 1024, 0, stream>>>(hf, dcb);
    ssd_k3<<<nblk, 256, 0, stream>>>(C, hf, dfs, Y);
}

// Round 3
// 62.278 us; speedup vs baseline: 2.0946x; 1.2702x over previous
//
#include <hip/hip_runtime.h>
#include <hip/hip_bf16.h>
#include <math.h>

// Problem constants (b=2, L=4096, H=16, dh=ds=64, CHUNK=64)
#define LSEQ 4096
#define NH   16
#define DH   64
#define CH   64
#define NCH  64
#define LDT  72   // bf16 LDS row stride: 144B rows -> 16B aligned, balanced b128 reads

typedef __attribute__((ext_vector_type(8))) short bf16x8;
typedef __attribute__((ext_vector_type(4))) short s16x4;
typedef __attribute__((ext_vector_type(4))) float f32x4;

#define MFMA16(a, b, c) __builtin_amdgcn_mfma_f32_16x16x32_bf16((a), (b), (c), 0, 0, 0)

__device__ __forceinline__ float4 ld4(const float* p) {
    return *reinterpret_cast<const float4*>(p);
}
__device__ __forceinline__ short f2b(float x) {
    __hip_bfloat16 h = __float2bfloat16(x);
    return *reinterpret_cast<short*>(&h);
}
__device__ __forceinline__ float b2f(short s) {
    union { unsigned u; float f; } v;
    v.u = ((unsigned)(unsigned short)s) << 16;
    return v.f;
}
__device__ __forceinline__ s16x4 pack4(float a, float b, float c, float d) {
    s16x4 r; r.x = f2b(a); r.y = f2b(b); r.z = f2b(c); r.w = f2b(d); return r;
}

// ---------------------------------------------------------------------------
// Kernel 1: per-chunk MFMA work. One block per (b,h,n). 256 threads = 4 waves.
// Fragment map (m89-verified, 16x16x32 bf16):
//   A: lane supplies A[row = rb + lane&15][k = 8*(lane>>4) + i]
//   B: lane supplies B[k][col = 16n + lane&15]
//   D: lane holds D[row = rb + 4*(lane>>4)+r][col = 16n + lane&15]
// Orientation rule: choose A so that D's 4 consecutive rows map to the
// fastest-varying global dim -> all global stores are vectorized.
//   Y_intra^T = MFMA(A=X^T, B=T)      D[d][i] -> Y[i][d] float4-equivalent (bf16x4 to yw)
//   h_final   = MFMA(A=B'^T, B=X^T)   D[s][d] -> hf[d][s] bf16x4
// LDS: sXT [d][c], sBT [s][c] (dte-scaled in place), sB [c][s] (reused as sT),
//      sC [i][d].  4 tiles = 36.9 KB -> 4 blocks/CU.
// ---------------------------------------------------------------------------
__global__ __launch_bounds__(256) void ssd_k1(
    const float* __restrict__ X, const float* __restrict__ A,
    const float* __restrict__ B, const float* __restrict__ C,
    const float* __restrict__ l2ab, const float* __restrict__ l2b,
    const float* __restrict__ ema,
    unsigned short* __restrict__ yw, unsigned short* __restrict__ hf,
    float* __restrict__ dcb, float* __restrict__ dfs)
{
    __shared__ __align__(16) short sXT[CH * LDT];
    __shared__ __align__(16) short sBT[CH * LDT];
    __shared__ __align__(16) short sB [CH * LDT];   // reused as sT after CB
    __shared__ __align__(16) short sC [CH * LDT];
    __shared__ float sA[CH], sAcs[CH], sDte[CH], sEp[CH], sEn[CH], red[4];

    const int tid  = threadIdx.x;
    const int blk  = blockIdx.x;
    const int nidx = blk & (NCH - 1);
    const int h    = (blk >> 6) & (NH - 1);
    const int bb   = blk >> 10;
    const size_t base = ((size_t)(bb * LSEQ + nidx * CH) * NH + h) * DH;

    // ---- stage: X -> sXT (scatter transpose), B -> sB + sBT, C -> sC ----
    #pragma unroll
    for (int m = 0; m < 4; ++m) {
        int p = tid + 256 * m;
        int c = p >> 4, q = p & 15, d0 = q * 4;
        size_t g = base + (size_t)c * 1024 + d0;
        float4 xv = ld4(&X[g]);
        float4 bv = ld4(&B[g]);
        float4 cv = ld4(&C[g]);
        *reinterpret_cast<s16x4*>(&sC[c * LDT + d0]) = pack4(cv.x, cv.y, cv.z, cv.w);
        *reinterpret_cast<s16x4*>(&sB[c * LDT + d0]) = pack4(bv.x, bv.y, bv.z, bv.w);
        float xf[4] = {xv.x, xv.y, xv.z, xv.w};
        float bf[4] = {bv.x, bv.y, bv.z, bv.w};
        #pragma unroll
        for (int ee = 0; ee < 4; ++ee) {
            int e = (ee + q) & 3;   // lane-staggered order reduces write-bank aliasing
            sXT[(d0 + e) * LDT + c] = f2b(xf[e]);
            sBT[(d0 + e) * LDT + c] = f2b(bf[e]);
        }
    }
    if (tid < CH) sA[tid] = A[(size_t)(bb * LSEQ + nidx * CH + tid) * NH + h];
    __syncthreads();

    const int lane = tid & 63;
    const int w    = tid >> 6;
    const int rb   = 16 * w;
    const int fr   = lane & 15;
    const int g4   = 4 * (lane >> 4);
    const int ko   = 8 * (lane >> 4);
    const f32x4 zf = {0.f, 0.f, 0.f, 0.f};

    // ---- phase 2: BX = B^T X; surprise = ||BX||^2 ----
    f32x4 acc0[4] = {zf, zf, zf, zf};
    #pragma unroll
    for (int k0 = 0; k0 < 64; k0 += 32) {
        bf16x8 a = *reinterpret_cast<const bf16x8*>(&sBT[(rb + fr) * LDT + k0 + ko]);
        #pragma unroll
        for (int n = 0; n < 4; ++n) {
            bf16x8 b = *reinterpret_cast<const bf16x8*>(&sXT[(16 * n + fr) * LDT + k0 + ko]);
            acc0[n] = MFMA16(a, b, acc0[n]);
        }
    }
    float ss = 0.f;
    #pragma unroll
    for (int n = 0; n < 4; ++n)
        #pragma unroll
        for (int r = 0; r < 4; ++r) ss += acc0[n][r] * acc0[n][r];
    #pragma unroll
    for (int off = 32; off > 0; off >>= 1) ss += __shfl_down(ss, off, 64);
    if (lane == 0) red[w] = ss;
    __syncthreads();

    // ---- phase 3: gate + wave-parallel scan + exp tables (wave 0) ----
    if (tid < CH) {
        float surprise = (red[0] + red[1] + red[2] + red[3]) * (1.f / 4096.f);
        float l2c   = fminf(fmaxf(l2ab[h], -3.32f), -0.015f);
        float ab_   = 1.f - exp2f(l2c);
        float bt    = exp2f(fminf(fmaxf(l2b[h], -2.f), 2.f));
        float nrm   = surprise / (ema[h] + 1e-6f);
        float boost = fmaxf(tanhf(bt * nrm), 0.f);
        float alpha = fminf(fmaxf(ab_ + (1.f - ab_) * boost, 0.01f), 0.999f);
        float scale = 1.f - alpha;
        float v = sA[tid] * scale;
        #pragma unroll
        for (int off = 1; off < 64; off <<= 1) {
            float t = __shfl_up(v, off, 64);
            if (tid >= off) v += t;
        }
        float tot = __shfl(v, 63, 64);
        float ep  = expf(v);
        sAcs[tid] = v;
        sEp[tid]  = ep;
        sEn[tid]  = expf(-v);
        sDte[tid] = expf(tot - v);
        dfs[(size_t)blk * CH + tid] = ep;
        if (tid == 63) dcb[blk] = expf(tot);
    }
    __syncthreads();

    // ---- phase 4a: sBT -> B'^T in place (scale col c by dte[c]) ----
    #pragma unroll
    for (int m = 0; m < 4; ++m) {
        int p = tid + 256 * m;
        int s = p >> 4, c0 = 4 * (p & 15);
        s16x4 v = *reinterpret_cast<s16x4*>(&sBT[s * LDT + c0]);
        v.x = f2b(b2f(v.x) * sDte[c0]);
        v.y = f2b(b2f(v.y) * sDte[c0 + 1]);
        v.z = f2b(b2f(v.z) * sDte[c0 + 2]);
        v.w = f2b(b2f(v.w) * sDte[c0 + 3]);
        *reinterpret_cast<s16x4*>(&sBT[s * LDT + c0]) = v;
    }

    // ---- phase 4b: CB = C B^T ----
    f32x4 acc1[4] = {zf, zf, zf, zf};
    #pragma unroll
    for (int k0 = 0; k0 < 64; k0 += 32) {
        bf16x8 a = *reinterpret_cast<const bf16x8*>(&sC[(rb + fr) * LDT + k0 + ko]);
        #pragma unroll
        for (int n = 0; n < 4; ++n) {
            bf16x8 b = *reinterpret_cast<const bf16x8*>(&sB[(16 * n + fr) * LDT + k0 + ko]);
            acc1[n] = MFMA16(a, b, acc1[n]);
        }
    }
    __syncthreads();   // all sB reads done -> safe to overwrite as sT

    // ---- phase 4c: T[i][j] = (j<=i) ? exp(Acs_i)*exp(-Acs_j)*CB : 0 ----
    short* sT = sB;
    #pragma unroll
    for (int n = 0; n < 4; ++n)
        #pragma unroll
        for (int r = 0; r < 4; ++r) {
            int i = rb + g4 + r;
            int j = 16 * n + fr;
            float val = (j <= i) ? sEp[i] * sEn[j] * acc1[n][r] : 0.f;
            sT[i * LDT + j] = f2b(val);
        }
    __syncthreads();   // sT + scaled sBT visible to all

    // ---- phase 5: Y_intra^T = MFMA(A=sXT, B=sT)   D[d][i]
    //      phase 6: h_final   = MFMA(A=sBT', B=sXT) D[s][d] ----
    f32x4 acc2[4] = {zf, zf, zf, zf};
    f32x4 acc3[4] = {zf, zf, zf, zf};
    #pragma unroll
    for (int k0 = 0; k0 < 64; k0 += 32) {
        bf16x8 aX = *reinterpret_cast<const bf16x8*>(&sXT[(rb + fr) * LDT + k0 + ko]);
        bf16x8 aB = *reinterpret_cast<const bf16x8*>(&sBT[(rb + fr) * LDT + k0 + ko]);
        #pragma unroll
        for (int n = 0; n < 4; ++n) {
            bf16x8 bT = *reinterpret_cast<const bf16x8*>(&sT [(16 * n + fr) * LDT + k0 + ko]);
            bf16x8 bX = *reinterpret_cast<const bf16x8*>(&sXT[(16 * n + fr) * LDT + k0 + ko]);
            acc2[n] = MFMA16(aX, bT, acc2[n]);
            acc3[n] = MFMA16(aB, bX, acc3[n]);
        }
    }
    // yw[i][d] <- Y_intra (bf16x4 vector stores, d fastest)
    // hf[d][s] <- h_final (bf16x4 vector stores, s fastest)
    #pragma unroll
    for (int n = 0; n < 4; ++n) {
        int colI = 16 * n + fr;
        s16x4 y4 = pack4(acc2[n][0], acc2[n][1], acc2[n][2], acc2[n][3]);
        s16x4 h4 = pack4(acc3[n][0], acc3[n][1], acc3[n][2], acc3[n][3]);
        *reinterpret_cast<s16x4*>(&yw[(size_t)blk * 4096 + colI * 64 + rb + g4]) = y4;
        *reinterpret_cast<s16x4*>(&hf[(size_t)blk * 4096 + colI * 64 + rb + g4]) = h4;
    }
}

// ---------------------------------------------------------------------------
// Kernel 2: sequential inter-chunk scan, in place on bf16 hf.
// 256 blocks x 256 threads; each thread owns 2 state elements (one uint).
// Depth-8 load pipelining: loads are independent of the carry chain.
// ---------------------------------------------------------------------------
__global__ __launch_bounds__(256) void ssd_k2(
    unsigned int* __restrict__ hfU, const float* __restrict__ dcb)
{
    __shared__ float sdc[NCH];
    const int tid = threadIdx.x;
    const int bh  = blockIdx.x >> 3;
    const int sub = blockIdx.x & 7;
    if (tid < NCH) sdc[tid] = dcb[bh * NCH + tid];
    __syncthreads();
    const size_t base = (size_t)bh * NCH * 2048 + sub * 256 + tid;  // uint index

    float c0 = 0.f, c1 = 0.f;
    unsigned int cur[8];
    #pragma unroll
    for (int kk = 0; kk < 8; ++kk) cur[kk] = hfU[base + (size_t)kk * 2048];
    #pragma unroll
    for (int kb = 0; kb < 8; ++kb) {
        unsigned int nxt[8];
        if (kb < 7) {
            #pragma unroll
            for (int kk = 0; kk < 8; ++kk)
                nxt[kk] = hfU[base + (size_t)(8 * kb + 8 + kk) * 2048];
        }
        #pragma unroll
        for (int kk = 0; kk < 8; ++kk) {
            int k = 8 * kb + kk;
            unsigned int u = cur[kk];
            union { unsigned int q; float f; } lo, hi;
            lo.q = u << 16;
            hi.q = u & 0xffff0000u;
            unsigned int packed = (unsigned int)(unsigned short)f2b(c0)
                                | ((unsigned int)(unsigned short)f2b(c1) << 16);
            hfU[base + (size_t)k * 2048] = packed;
            float d = sdc[k];
            c0 = fmaf(d, c0, lo.f);
            c1 = fmaf(d, c1, hi.f);
        }
        if (kb < 7) {
            #pragma unroll
            for (int kk = 0; kk < 8; ++kk) cur[kk] = nxt[kk];
        }
    }
}

// ---------------------------------------------------------------------------
// Kernel 3: Y[i][p] = yw[i][p] + dfs[i] * (C @ h_inter)[i][p].
// Y_inter^T = MFMA(A=sHt (h^T[p][s], the native hf layout), B=sC2 (C[i][s]))
// -> D[p][i]; stores to Y[i*1024+p] are float4 (p fastest).
// One block per (b,h,n). 256 threads. ~18.7 KB LDS -> 8 blocks/CU.
// ---------------------------------------------------------------------------
__global__ __launch_bounds__(256) void ssd_k3(
    const float* __restrict__ C, const unsigned short* __restrict__ hI,
    const unsigned short* __restrict__ yw, const float* __restrict__ dfs,
    float* __restrict__ Y)
{
    __shared__ __align__(16) short sHt[CH * LDT];
    __shared__ __align__(16) short sC2[CH * LDT];
    __shared__ float sF[CH];

    const int tid  = threadIdx.x;
    const int blk  = blockIdx.x;
    const int nidx = blk & (NCH - 1);
    const int h    = (blk >> 6) & (NH - 1);
    const int bb   = blk >> 10;
    const size_t base = ((size_t)(bb * LSEQ + nidx * CH) * NH + h) * DH;

    // stage h^T (bf16 already; plain copy) and C (f32 -> bf16)
    #pragma unroll
    for (int m = 0; m < 2; ++m) {
        int idx = tid + 256 * m;              // 0..511, 8 shorts each
        int row = idx >> 3, c8 = (idx & 7) * 8;
        bf16x8 v = *reinterpret_cast<const bf16x8*>(&hI[(size_t)blk * 4096 + row * 64 + c8]);
        *reinterpret_cast<bf16x8*>(&sHt[row * LDT + c8]) = v;
    }
    #pragma unroll
    for (int m = 0; m < 4; ++m) {
        int p = tid + 256 * m;
        int row = p >> 4, d0 = (p & 15) * 4;
        float4 cv = ld4(&C[base + (size_t)row * 1024 + d0]);
        *reinterpret_cast<s16x4*>(&sC2[row * LDT + d0]) = pack4(cv.x, cv.y, cv.z, cv.w);
    }
    if (tid < CH) sF[tid] = dfs[(size_t)blk * CH + tid];
    __syncthreads();

    const int lane = tid & 63;
    const int w    = tid >> 6;
    const int rb   = 16 * w;
    const int fr   = lane & 15;
    const int g4   = 4 * (lane >> 4);
    const int ko   = 8 * (lane >> 4);
    const f32x4 zf = {0.f, 0.f, 0.f, 0.f};

    f32x4 acc[4] = {zf, zf, zf, zf};
    #pragma unroll
    for (int k0 = 0; k0 < 64; k0 += 32) {
        bf16x8 a = *reinterpret_cast<const bf16x8*>(&sHt[(rb + fr) * LDT + k0 + ko]);
        #pragma unroll
        for (int n = 0; n < 4; ++n) {
            bf16x8 b = *reinterpret_cast<const bf16x8*>(&sC2[(16 * n + fr) * LDT + k0 + ko]);
            acc[n] = MFMA16(a, b, acc[n]);
        }
    }
    #pragma unroll
    for (int n = 0; n < 4; ++n) {
        int i  = 16 * n + fr;           // D col
        int p0 = rb + g4;               // D rows (4 consecutive p)
        float f = sF[i];
        const unsigned short* ywp = &yw[(size_t)blk * 4096 + i * 64 + p0];
        float4 o;
        o.x = fmaf(f, acc[n][0], b2f((short)ywp[0]));
        o.y = fmaf(f, acc[n][1], b2f((short)ywp[1]));
        o.z = fmaf(f, acc[n][2], b2f((short)ywp[2]));
        o.w = fmaf(f, acc[n][3], b2f((short)ywp[3]));
        *reinterpret_cast<float4*>(&Y[base + (size_t)i * 1024 + p0]) = o;
    }
}

// ---------------------------------------------------------------------------
extern "C" void kernel_launch(void* const* d_in, const int* in_sizes, int n_in,
                              void* d_out, int out_size, void* d_ws, size_t ws_size,
                              hipStream_t stream)
{
    const float* X    = (const float*)d_in[0];
    const float* A    = (const float*)d_in[1];
    const float* B    = (const float*)d_in[2];
    const float* C    = (const float*)d_in[3];
    const float* l2ab = (const float*)d_in[4];
    const float* l2b  = (const float*)d_in[5];
    const float* ema  = (const float*)d_in[6];
    float* Y = (float*)d_out;

    // ws layout: hf bf16 [8388608] | yw bf16 [8388608] | dcb f32 [2048] | dfs f32 [131072]
    // total = 34,086,912 bytes
    unsigned short* hf = (unsigned short*)d_ws;
    unsigned short* yw = hf + (size_t)8388608;
    float* dcb = (float*)(yw + (size_t)8388608);
    float* dfs = dcb + 2048;

    const int nblk = 2 * NH * NCH;   // 2048
    ssd_k1<<<nblk, 256, 0, stream>>>(X, A, B, C, l2ab, l2b, ema, yw, hf, dcb, dfs);
    ssd_k2<<<256, 256, 0, stream>>>((unsigned int*)hf, dcb);
    ssd_k3<<<nblk, 256, 0, stream>>>(C, hf, yw, dfs, Y);
}

// Round 4
// 57.974 us; speedup vs baseline: 2.2501x; 1.0742x over previous
//
#include <hip/hip_runtime.h>
#include <hip/hip_bf16.h>
#include <math.h>

// Problem constants (b=2, L=4096, H=16, dh=ds=64, CHUNK=64)
#define LSEQ 4096
#define NH   16
#define DH   64
#define CH   64
#define NCH  64
#define LDT  72   // bf16 LDS row stride (144B): natural reads/writes <=2-way banks

typedef __attribute__((ext_vector_type(8))) short bf16x8;
typedef __attribute__((ext_vector_type(4))) short s16x4;
typedef __attribute__((ext_vector_type(4))) float f32x4;

#define MFMA16(a, b, c) __builtin_amdgcn_mfma_f32_16x16x32_bf16((a), (b), (c), 0, 0, 0)

__device__ __forceinline__ float4 ld4(const float* p) {
    return *reinterpret_cast<const float4*>(p);
}
__device__ __forceinline__ short f2b(float x) {
    __hip_bfloat16 h = __float2bfloat16(x);
    return *reinterpret_cast<short*>(&h);
}
__device__ __forceinline__ float b2f(short s) {
    union { unsigned u; float f; } v;
    v.u = ((unsigned)(unsigned short)s) << 16;
    return v.f;
}
__device__ __forceinline__ s16x4 pack4(float a, float b, float c, float d) {
    s16x4 r; r.x = f2b(a); r.y = f2b(b); r.z = f2b(c); r.w = f2b(d); return r;
}
__device__ __forceinline__ uint2 sx2(uint2 v, int m) {
    uint2 r;
    r.x = (unsigned)__shfl_xor((int)v.x, m, 64);
    r.y = (unsigned)__shfl_xor((int)v.y, m, 64);
    return r;
}
// extract short #g (0..3) from a uint2 (== short4)
__device__ __forceinline__ short ext4(uint2 u, int g) {
    unsigned word = (g & 2) ? u.y : u.x;
    return (short)((g & 1) ? (word >> 16) : (word & 0xffffu));
}

// ---------------------------------------------------------------------------
// Kernel 1: per-chunk MFMA work. One block per (b,h,n). 256 threads = 4 waves.
// Gram-trick schedule (4 barriers, 3 LDS tiles, 27.7 KB -> 5 blocks/CU):
//   stage naturals X->R1, B->R2, C->R3 (vectorized, conflict-free)
//   sync0; phase2: GX=X.X^T, GB=B.B^T, CB=C.B^T (all natural); ss=sum GX*GB
//   sync1; gate+scan redundantly in every wave (shfl, no LDS tables);
//          T -> R3 (C dead); read 4x4 blocks of R1,R2 + bfly-transpose in reg
//   sync2; write XT -> R1, dte-scaled B'^T -> R2 (in place)
//   sync3; Y_intra^T = MFMA(A=XT,B=T) -> yw ; h_final = MFMA(A=B'T,B=XT) -> hf
// Fragment map (m89-verified 16x16x32 bf16):
//   A: lane = A[row=rb+(lane&15)][k=8*(lane>>4)+i]; B: [k][col=16n+(lane&15)]
//   D: lane holds D[row=rb+4*(lane>>4)+r][col=16n+(lane&15)]
// ---------------------------------------------------------------------------
__global__ __launch_bounds__(256) void ssd_k1(
    const float* __restrict__ X, const float* __restrict__ A,
    const float* __restrict__ B, const float* __restrict__ C,
    const float* __restrict__ l2ab, const float* __restrict__ l2b,
    const float* __restrict__ ema,
    unsigned short* __restrict__ yw, unsigned short* __restrict__ hf,
    float* __restrict__ dcb, float* __restrict__ dfs)
{
    __shared__ __align__(16) short R1[CH * LDT];   // X nat -> XT
    __shared__ __align__(16) short R2[CH * LDT];   // B nat -> B'T (dte-scaled)
    __shared__ __align__(16) short R3[CH * LDT];   // C nat -> T
    __shared__ __align__(16) float red[4];

    const int tid  = threadIdx.x;
    const int blk  = blockIdx.x;
    const int nidx = blk & (NCH - 1);
    const int h    = (blk >> 6) & (NH - 1);
    const int bb   = blk >> 10;
    const size_t base = ((size_t)(bb * LSEQ + nidx * CH) * NH + h) * DH;

    const int lane = tid & 63;
    const int w    = tid >> 6;
    const int rb   = 16 * w;
    const int fr   = lane & 15;
    const int gq   = lane >> 4;          // 0..3
    const int g4   = 4 * gq;
    const int ko   = 8 * gq;

    // ---- stage naturals (pure vectorized b64 LDS writes) ----
    #pragma unroll
    for (int m = 0; m < 4; ++m) {
        int p = tid + 256 * m;
        int c = p >> 4, d0 = (p & 15) * 4;
        size_t g = base + (size_t)c * 1024 + d0;
        float4 xv = ld4(&X[g]);
        float4 bv = ld4(&B[g]);
        float4 cv = ld4(&C[g]);
        *reinterpret_cast<s16x4*>(&R1[c * LDT + d0]) = pack4(xv.x, xv.y, xv.z, xv.w);
        *reinterpret_cast<s16x4*>(&R2[c * LDT + d0]) = pack4(bv.x, bv.y, bv.z, bv.w);
        *reinterpret_cast<s16x4*>(&R3[c * LDT + d0]) = pack4(cv.x, cv.y, cv.z, cv.w);
    }
    // per-lane A value (position = lane), redundant across waves
    float aval = A[(size_t)(bb * LSEQ + nidx * CH + lane) * NH + h];
    __syncthreads();   // sync0

    const f32x4 zf = {0.f, 0.f, 0.f, 0.f};

    // ---- phase 2: GX, GB, CB on natural tiles ----
    f32x4 aGX[4] = {zf, zf, zf, zf};
    f32x4 aGB[4] = {zf, zf, zf, zf};
    f32x4 aCB[4] = {zf, zf, zf, zf};
    #pragma unroll
    for (int k0 = 0; k0 < 64; k0 += 32) {
        bf16x8 aX = *reinterpret_cast<const bf16x8*>(&R1[(rb + fr) * LDT + k0 + ko]);
        bf16x8 aB = *reinterpret_cast<const bf16x8*>(&R2[(rb + fr) * LDT + k0 + ko]);
        bf16x8 aC = *reinterpret_cast<const bf16x8*>(&R3[(rb + fr) * LDT + k0 + ko]);
        #pragma unroll
        for (int n = 0; n < 4; ++n) {
            bf16x8 bX = *reinterpret_cast<const bf16x8*>(&R1[(16 * n + fr) * LDT + k0 + ko]);
            bf16x8 bB = *reinterpret_cast<const bf16x8*>(&R2[(16 * n + fr) * LDT + k0 + ko]);
            aGX[n] = MFMA16(aX, bX, aGX[n]);
            aGB[n] = MFMA16(aB, bB, aGB[n]);
            aCB[n] = MFMA16(aC, bB, aCB[n]);
        }
    }
    float ss = 0.f;
    #pragma unroll
    for (int n = 0; n < 4; ++n)
        #pragma unroll
        for (int r = 0; r < 4; ++r) ss += aGX[n][r] * aGB[n][r];
    #pragma unroll
    for (int off = 32; off > 0; off >>= 1) ss += __shfl_down(ss, off, 64);
    if (lane == 0) red[w] = ss;
    __syncthreads();   // sync1

    // ---- gate + scan, redundantly in every wave (no LDS tables) ----
    float4 rv = *reinterpret_cast<const float4*>(red);   // broadcast read
    float surprise = (rv.x + rv.y + rv.z + rv.w) * (1.f / 4096.f);
    float l2c   = fminf(fmaxf(l2ab[h], -3.32f), -0.015f);
    float ab_   = 1.f - exp2f(l2c);
    float bt    = exp2f(fminf(fmaxf(l2b[h], -2.f), 2.f));
    float nrm   = surprise / (ema[h] + 1e-6f);
    float boost = fmaxf(tanhf(bt * nrm), 0.f);
    float alpha = fminf(fmaxf(ab_ + (1.f - ab_) * boost, 0.01f), 0.999f);
    float scale = 1.f - alpha;
    float v = aval * scale;
    #pragma unroll
    for (int off = 1; off < 64; off <<= 1) {
        float t = __shfl_up(v, off, 64);
        if (lane >= off) v += t;
    }
    float tot  = __shfl(v, 63, 64);
    float epv  = __expf(v);          // exp(Acs[lane])
    float env  = __expf(-v);
    float dtev = __expf(tot - v);    // decay_to_end[lane]
    if (w == 0) {
        dfs[(size_t)blk * CH + lane] = epv;
        if (lane == 63) dcb[blk] = __expf(tot);
    }

    // ---- T[i][j] = (j<=i) ? exp(Acs_i - Acs_j)*CB[i][j] : 0  -> R3 ----
    {
        float epi[4], enj[4];
        #pragma unroll
        for (int r = 0; r < 4; ++r) epi[r] = __shfl(epv, rb + g4 + r, 64);
        #pragma unroll
        for (int n = 0; n < 4; ++n) enj[n] = __shfl(env, 16 * n + fr, 64);
        #pragma unroll
        for (int n = 0; n < 4; ++n)
            #pragma unroll
            for (int r = 0; r < 4; ++r) {
                int i = rb + g4 + r, j = 16 * n + fr;
                float val = (j <= i) ? epi[r] * enj[n] * aCB[n][r] : 0.f;
                R3[i * LDT + j] = f2b(val);
            }
    }

    // ---- read 4x4 blocks of R1,R2; butterfly-transpose in registers ----
    // group = lanes {gq=0..3} sharing (w, fr): rows c0..c0+3, cols d0..d0+3
    s16x4 outX[4], outB[4];
    const int d0 = 4 * fr;
    #pragma unroll
    for (int m = 0; m < 4; ++m) {
        int c0 = 16 * w + 4 * m;
        uint2 mx = *reinterpret_cast<const uint2*>(&R1[(c0 + gq) * LDT + d0]);
        uint2 mb = *reinterpret_cast<const uint2*>(&R2[(c0 + gq) * LDT + d0]);
        // round 1 (^16): order pair as (even row, odd row)
        uint2 px = sx2(mx, 16), pb = sx2(mb, 16);
        uint2 xe = (gq & 1) ? px : mx, xo = (gq & 1) ? mx : px;
        uint2 be = (gq & 1) ? pb : mb, bo = (gq & 1) ? mb : pb;
        // round 2 (^32): other pair
        uint2 xpe = sx2(xe, 32), xpo = sx2(xo, 32);
        uint2 bpe = sx2(be, 32), bpo = sx2(bo, 32);
        uint2 xr0 = (gq & 2) ? xpe : xe, xr1 = (gq & 2) ? xpo : xo;
        uint2 xr2 = (gq & 2) ? xe : xpe, xr3 = (gq & 2) ? xo : xpo;
        uint2 br0 = (gq & 2) ? bpe : be, br1 = (gq & 2) ? bpo : bo;
        uint2 br2 = (gq & 2) ? be : bpe, br3 = (gq & 2) ? bo : bpo;
        // transposed row d0+gq, cols c0..c0+3
        s16x4 ox; ox.x = ext4(xr0, gq); ox.y = ext4(xr1, gq);
                  ox.z = ext4(xr2, gq); ox.w = ext4(xr3, gq);
        outX[m] = ox;
        // B side: scale col c by dte[c] while in registers
        float dt0 = __shfl(dtev, c0 + 0, 64), dt1 = __shfl(dtev, c0 + 1, 64);
        float dt2 = __shfl(dtev, c0 + 2, 64), dt3 = __shfl(dtev, c0 + 3, 64);
        s16x4 ob;
        ob.x = f2b(b2f(ext4(br0, gq)) * dt0);
        ob.y = f2b(b2f(ext4(br1, gq)) * dt1);
        ob.z = f2b(b2f(ext4(br2, gq)) * dt2);
        ob.w = f2b(b2f(ext4(br3, gq)) * dt3);
        outB[m] = ob;
    }
    __syncthreads();   // sync2 — all natural reads complete

    #pragma unroll
    for (int m = 0; m < 4; ++m) {
        int c0 = 16 * w + 4 * m;
        *reinterpret_cast<s16x4*>(&R1[(d0 + gq) * LDT + c0]) = outX[m];
        *reinterpret_cast<s16x4*>(&R2[(d0 + gq) * LDT + c0]) = outB[m];
    }
    __syncthreads();   // sync3 — XT, B'T, T all visible

    // ---- phase 5: Y_intra^T = MFMA(A=XT, B=T)   D[d][i]
    //      phase 6: h_final   = MFMA(A=B'T, B=XT) D[s][d] ----
    f32x4 acc2[4] = {zf, zf, zf, zf};
    f32x4 acc3[4] = {zf, zf, zf, zf};
    #pragma unroll
    for (int k0 = 0; k0 < 64; k0 += 32) {
        bf16x8 aX = *reinterpret_cast<const bf16x8*>(&R1[(rb + fr) * LDT + k0 + ko]);
        bf16x8 aB = *reinterpret_cast<const bf16x8*>(&R2[(rb + fr) * LDT + k0 + ko]);
        #pragma unroll
        for (int n = 0; n < 4; ++n) {
            bf16x8 bT = *reinterpret_cast<const bf16x8*>(&R3[(16 * n + fr) * LDT + k0 + ko]);
            bf16x8 bX = *reinterpret_cast<const bf16x8*>(&R1[(16 * n + fr) * LDT + k0 + ko]);
            acc2[n] = MFMA16(aX, bT, acc2[n]);
            acc3[n] = MFMA16(aB, bX, acc3[n]);
        }
    }
    // yw[i][d] <- Y_intra ; hf[d][s] <- h_final (bf16x4 vector stores)
    #pragma unroll
    for (int n = 0; n < 4; ++n) {
        int colI = 16 * n + fr;
        s16x4 y4 = pack4(acc2[n][0], acc2[n][1], acc2[n][2], acc2[n][3]);
        s16x4 h4 = pack4(acc3[n][0], acc3[n][1], acc3[n][2], acc3[n][3]);
        *reinterpret_cast<s16x4*>(&yw[(size_t)blk * 4096 + colI * 64 + rb + g4]) = y4;
        *reinterpret_cast<s16x4*>(&hf[(size_t)blk * 4096 + colI * 64 + rb + g4]) = h4;
    }
}

// ---------------------------------------------------------------------------
// Kernel 2: sequential inter-chunk scan, in place on bf16 hf.
// 256 blocks x 256 threads; each thread owns 2 state elements (one uint).
// ---------------------------------------------------------------------------
__global__ __launch_bounds__(256) void ssd_k2(
    unsigned int* __restrict__ hfU, const float* __restrict__ dcb)
{
    __shared__ float sdc[NCH];
    const int tid = threadIdx.x;
    const int bh  = blockIdx.x >> 3;
    const int sub = blockIdx.x & 7;
    if (tid < NCH) sdc[tid] = dcb[bh * NCH + tid];
    __syncthreads();
    const size_t base = (size_t)bh * NCH * 2048 + sub * 256 + tid;  // uint index

    float c0 = 0.f, c1 = 0.f;
    unsigned int cur[8];
    #pragma unroll
    for (int kk = 0; kk < 8; ++kk) cur[kk] = hfU[base + (size_t)kk * 2048];
    #pragma unroll
    for (int kb = 0; kb < 8; ++kb) {
        unsigned int nxt[8];
        if (kb < 7) {
            #pragma unroll
            for (int kk = 0; kk < 8; ++kk)
                nxt[kk] = hfU[base + (size_t)(8 * kb + 8 + kk) * 2048];
        }
        #pragma unroll
        for (int kk = 0; kk < 8; ++kk) {
            int k = 8 * kb + kk;
            unsigned int u = cur[kk];
            union { unsigned int q; float f; } lo, hi;
            lo.q = u << 16;
            hi.q = u & 0xffff0000u;
            unsigned int packed = (unsigned int)(unsigned short)f2b(c0)
                                | ((unsigned int)(unsigned short)f2b(c1) << 16);
            hfU[base + (size_t)k * 2048] = packed;
            float d = sdc[k];
            c0 = fmaf(d, c0, lo.f);
            c1 = fmaf(d, c1, hi.f);
        }
        if (kb < 7) {
            #pragma unroll
            for (int kk = 0; kk < 8; ++kk) cur[kk] = nxt[kk];
        }
    }
}

// ---------------------------------------------------------------------------
// Kernel 3: Y[i][p] = yw[i][p] + dfs[i] * (C @ h_inter)[i][p].
// Y_inter^T = MFMA(A=sHt (h^T[p][s], native hf layout), B=sC2 (C[i][s]))
// -> D[p][i]; float4 stores to Y (p fastest). One block per (b,h,n).
// ---------------------------------------------------------------------------
__global__ __launch_bounds__(256) void ssd_k3(
    const float* __restrict__ C, const unsigned short* __restrict__ hI,
    const unsigned short* __restrict__ yw, const float* __restrict__ dfs,
    float* __restrict__ Y)
{
    __shared__ __align__(16) short sHt[CH * LDT];
    __shared__ __align__(16) short sC2[CH * LDT];
    __shared__ float sF[CH];

    const int tid  = threadIdx.x;
    const int blk  = blockIdx.x;
    const int nidx = blk & (NCH - 1);
    const int h    = (blk >> 6) & (NH - 1);
    const int bb   = blk >> 10;
    const size_t base = ((size_t)(bb * LSEQ + nidx * CH) * NH + h) * DH;

    #pragma unroll
    for (int m = 0; m < 2; ++m) {
        int idx = tid + 256 * m;
        int row = idx >> 3, c8 = (idx & 7) * 8;
        bf16x8 v = *reinterpret_cast<const bf16x8*>(&hI[(size_t)blk * 4096 + row * 64 + c8]);
        *reinterpret_cast<bf16x8*>(&sHt[row * LDT + c8]) = v;
    }
    #pragma unroll
    for (int m = 0; m < 4; ++m) {
        int p = tid + 256 * m;
        int row = p >> 4, d0 = (p & 15) * 4;
        float4 cv = ld4(&C[base + (size_t)row * 1024 + d0]);
        *reinterpret_cast<s16x4*>(&sC2[row * LDT + d0]) = pack4(cv.x, cv.y, cv.z, cv.w);
    }
    if (tid < CH) sF[tid] = dfs[(size_t)blk * CH + tid];
    __syncthreads();

    const int lane = tid & 63;
    const int w    = tid >> 6;
    const int rb   = 16 * w;
    const int fr   = lane & 15;
    const int g4   = 4 * (lane >> 4);
    const int ko   = 8 * (lane >> 4);
    const f32x4 zf = {0.f, 0.f, 0.f, 0.f};

    f32x4 acc[4] = {zf, zf, zf, zf};
    #pragma unroll
    for (int k0 = 0; k0 < 64; k0 += 32) {
        bf16x8 a = *reinterpret_cast<const bf16x8*>(&sHt[(rb + fr) * LDT + k0 + ko]);
        #pragma unroll
        for (int n = 0; n < 4; ++n) {
            bf16x8 b = *reinterpret_cast<const bf16x8*>(&sC2[(16 * n + fr) * LDT + k0 + ko]);
            acc[n] = MFMA16(a, b, acc[n]);
        }
    }
    #pragma unroll
    for (int n = 0; n < 4; ++n) {
        int i  = 16 * n + fr;
        int p0 = rb + g4;
        float f = sF[i];
        const unsigned short* ywp = &yw[(size_t)blk * 4096 + i * 64 + p0];
        float4 o;
        o.x = fmaf(f, acc[n][0], b2f((short)ywp[0]));
        o.y = fmaf(f, acc[n][1], b2f((short)ywp[1]));
        o.z = fmaf(f, acc[n][2], b2f((short)ywp[2]));
        o.w = fmaf(f, acc[n][3], b2f((short)ywp[3]));
        *reinterpret_cast<float4*>(&Y[base + (size_t)i * 1024 + p0]) = o;
    }
}

// ---------------------------------------------------------------------------
extern "C" void kernel_launch(void* const* d_in, const int* in_sizes, int n_in,
                              void* d_out, int out_size, void* d_ws, size_t ws_size,
                              hipStream_t stream)
{
    const float* X    = (const float*)d_in[0];
    const float* A    = (const float*)d_in[1];
    const float* B    = (const float*)d_in[2];
    const float* C    = (const float*)d_in[3];
    const float* l2ab = (const float*)d_in[4];
    const float* l2b  = (const float*)d_in[5];
    const float* ema  = (const float*)d_in[6];
    float* Y = (float*)d_out;

    // ws layout: hf bf16 [8388608] | yw bf16 [8388608] | dcb f32 [2048] | dfs f32 [131072]
    unsigned short* hf = (unsigned short*)d_ws;
    unsigned short* yw = hf + (size_t)8388608;
    float* dcb = (float*)(yw + (size_t)8388608);
    float* dfs = dcb + 2048;

    const int nblk = 2 * NH * NCH;   // 2048
    ssd_k1<<<nblk, 256, 0, stream>>>(X, A, B, C, l2ab, l2b, ema, yw, hf, dcb, dfs);
    ssd_k2<<<256, 256, 0, stream>>>((unsigned int*)hf, dcb);
    ssd_k3<<<nblk, 256, 0, stream>>>(C, hf, yw, dfs, Y);
}